// Round 1
// baseline (1525.806 us; speedup 1.0000x reference)
//
#include <hip/hip_runtime.h>

#define M_DIM 4096
#define K_DIM 4096
#define N_DIM 16384

typedef float v4f __attribute__((ext_vector_type(4)));

// ---------------------------------------------------------------------------
// Kernel 1: per-token dynamic quantization of x.
// One block per row. scale = max(rowmax|x|/448, 1e-12); xq = fp8(x/scale).
// Division + RNE fp8 convert matches the reference's fp32 ops bitwise in-range.
// ---------------------------------------------------------------------------
__global__ __launch_bounds__(256) void quant_x_kernel(
    const float* __restrict__ x, unsigned char* __restrict__ xq,
    float* __restrict__ xs) {
  const int row = blockIdx.x;
  const int t = threadIdx.x;
  const float4* xr4 = (const float4*)(x + (size_t)row * K_DIM);

  float4 v[4];
  float am = 0.f;
#pragma unroll
  for (int i = 0; i < 4; ++i) {
    v[i] = xr4[t + 256 * i];
    am = fmaxf(am, fmaxf(fmaxf(fabsf(v[i].x), fabsf(v[i].y)),
                         fmaxf(fabsf(v[i].z), fabsf(v[i].w))));
  }
  // wave64 butterfly reduce, then 4-wave LDS reduce
#pragma unroll
  for (int off = 32; off > 0; off >>= 1)
    am = fmaxf(am, __shfl_xor(am, off, 64));
  __shared__ float red[4];
  if ((t & 63) == 0) red[t >> 6] = am;
  __syncthreads();
  am = fmaxf(fmaxf(red[0], red[1]), fmaxf(red[2], red[3]));

  const float scale = fmaxf(am / 448.0f, 1e-12f);
  if (t == 0) xs[row] = scale;

  uint32_t* out = (uint32_t*)(xq + (size_t)row * K_DIM);
#pragma unroll
  for (int i = 0; i < 4; ++i) {
    float a0 = v[i].x / scale, a1 = v[i].y / scale;
    float a2 = v[i].z / scale, a3 = v[i].w / scale;
    uint32_t p = __builtin_amdgcn_cvt_pk_fp8_f32(a0, a1, 0, false);
    p = __builtin_amdgcn_cvt_pk_fp8_f32(a2, a3, p, true);
    out[t + 256 * i] = p;
  }
}

// ---------------------------------------------------------------------------
// Kernel 2: repack weight fp32 codes -> fp8 bytes (exact: values already on
// the e4m3 grid). 4 elements/thread.
// ---------------------------------------------------------------------------
__global__ __launch_bounds__(256) void quant_w_kernel(
    const float4* __restrict__ w, uint32_t* __restrict__ wq) {
  const int i = blockIdx.x * 256 + threadIdx.x;
  float4 v = w[i];
  uint32_t p = __builtin_amdgcn_cvt_pk_fp8_f32(v.x, v.y, 0, false);
  p = __builtin_amdgcn_cvt_pk_fp8_f32(v.z, v.w, p, true);
  wq[i] = p;
}

// ---------------------------------------------------------------------------
// Kernel 3: fp8 GEMM, m97 structure. C[m,n] = sum_k xq[m,k]*wq[n,k], epilogue
// y = C * xs[m] * wscale[n] + bias[n].
// Block: 256 thr = 4 waves (2x2, each 64x64). Tile 128x128, BK=64 bytes.
// ---------------------------------------------------------------------------
__device__ __forceinline__ void async_copy16(const void* g, void* l) {
  __builtin_amdgcn_global_load_lds(
      (const __attribute__((address_space(1))) void*)g,
      (__attribute__((address_space(3))) void*)l, 16, 0, 0);
}

__global__ __launch_bounds__(256) void gemm_fp8_kernel(
    const unsigned char* __restrict__ Aq,  // [M,K] fp8
    const unsigned char* __restrict__ Bq,  // [N,K] fp8
    const float* __restrict__ xs,          // [M]
    const float* __restrict__ wscale,      // [N]
    const float* __restrict__ bias,        // [N]
    float* __restrict__ y) {               // [M,N]
  constexpr int BM = 128, BN = 128, BK = 64;
  __shared__ __align__(16) unsigned char smem[(BM + BN) * BK];  // 16 KiB
  unsigned char* sA = smem;
  unsigned char* sB = smem + BM * BK;

  const int t = threadIdx.x;
  const int bm = blockIdx.y * BM;
  const int bn = blockIdx.x * BN;

  // staging: tile is 512 chunks of 16B; thread t stages chunks t and t+256.
  // chunk c -> row c/4, byte-col (c%4)*16 ; LDS dst = smem + c*16
  // (wave-uniform base + lane*16 — required by global_load_lds).
  const int srow = t >> 2;
  const int scol = (t & 3) * 16;
  const unsigned char* Ag0 = Aq + (size_t)(bm + srow) * K_DIM + scol;
  const unsigned char* Ag1 = Aq + (size_t)(bm + srow + 64) * K_DIM + scol;
  const unsigned char* Bg0 = Bq + (size_t)(bn + srow) * K_DIM + scol;
  const unsigned char* Bg1 = Bq + (size_t)(bn + srow + 64) * K_DIM + scol;

  const int lane = t & 63;
  const int w = t >> 6;
  const int wm = (w >> 1) * 64;
  const int wn = (w & 1) * 64;
  const int lrow = lane & 15;   // A-row / B-col / C-col
  const int lq = lane >> 4;     // quad: k-base (lq*8), C-row base (lq*4)

  v4f acc[4][4];
#pragma unroll
  for (int i = 0; i < 4; ++i)
#pragma unroll
    for (int j = 0; j < 4; ++j) acc[i][j] = {0.f, 0.f, 0.f, 0.f};

  for (int k0 = 0; k0 < K_DIM; k0 += BK) {
    __syncthreads();
    async_copy16(Ag0 + k0, sA + t * 16);
    async_copy16(Ag1 + k0, sA + (t + 256) * 16);
    async_copy16(Bg0 + k0, sB + t * 16);
    async_copy16(Bg1 + k0, sB + (t + 256) * 16);
    __syncthreads();  // compiler emits s_waitcnt vmcnt(0) before s_barrier

#pragma unroll
    for (int kk = 0; kk < BK; kk += 32) {
      long long a_frag[4], b_frag[4];
#pragma unroll
      for (int i = 0; i < 4; ++i)
        a_frag[i] =
            *(const long long*)(sA + (wm + i * 16 + lrow) * BK + kk + lq * 8);
#pragma unroll
      for (int j = 0; j < 4; ++j)
        b_frag[j] =
            *(const long long*)(sB + (wn + j * 16 + lrow) * BK + kk + lq * 8);
#pragma unroll
      for (int i = 0; i < 4; ++i)
#pragma unroll
        for (int j = 0; j < 4; ++j)
          acc[i][j] = __builtin_amdgcn_mfma_f32_16x16x32_fp8_fp8(
              a_frag[i], b_frag[j], acc[i][j], 0, 0, 0);
    }
  }

  // epilogue: C/D layout col=lane&15, row=(lane>>4)*4+reg
  float xsv[4][4];
#pragma unroll
  for (int i = 0; i < 4; ++i)
#pragma unroll
    for (int r = 0; r < 4; ++r)
      xsv[i][r] = xs[bm + wm + i * 16 + lq * 4 + r];

#pragma unroll
  for (int j = 0; j < 4; ++j) {
    const int col = bn + wn + j * 16 + lrow;
    const float wsc = wscale[col];
    const float bv = bias[col];
#pragma unroll
    for (int i = 0; i < 4; ++i) {
      const int row0 = bm + wm + i * 16 + lq * 4;
#pragma unroll
      for (int r = 0; r < 4; ++r)
        y[(size_t)(row0 + r) * N_DIM + col] =
            acc[i][j][r] * xsv[i][r] * wsc + bv;
    }
  }
}

// ---------------------------------------------------------------------------
extern "C" void kernel_launch(void* const* d_in, const int* in_sizes, int n_in,
                              void* d_out, int out_size, void* d_ws,
                              size_t ws_size, hipStream_t stream) {
  const float* x = (const float*)d_in[0];       // [M,K]
  const float* w = (const float*)d_in[1];       // [N,K] fp8 codes in fp32
  const float* wscale = (const float*)d_in[2];  // [N,1]
  const float* bias = (const float*)d_in[3];    // [N]
  float* y = (float*)d_out;                     // [M,N]

  unsigned char* xq = (unsigned char*)d_ws;                  // 16 MiB
  unsigned char* wq = xq + (size_t)M_DIM * K_DIM;            // 64 MiB
  float* xs = (float*)(wq + (size_t)N_DIM * K_DIM);          // 16 KiB

  quant_x_kernel<<<M_DIM, 256, 0, stream>>>(x, xq, xs);
  quant_w_kernel<<<((size_t)N_DIM * K_DIM / 4) / 256, 256, 0, stream>>>(
      (const float4*)w, (uint32_t*)wq);
  dim3 grid(N_DIM / 128, M_DIM / 128);
  gemm_fp8_kernel<<<grid, 256, 0, stream>>>(xq, wq, xs, wscale, bias, y);
}

// Round 2
// 985.139 us; speedup vs baseline: 1.5488x; 1.5488x over previous
//
#include <hip/hip_runtime.h>

#define M_DIM 4096
#define K_DIM 4096
#define N_DIM 16384

typedef float v4f __attribute__((ext_vector_type(4)));

// ---------------------------------------------------------------------------
// Kernel 1: per-token dynamic quantization of x.
// One block per row. scale = max(rowmax|x|/448, 1e-12); xq = fp8(x/scale).
// ---------------------------------------------------------------------------
__global__ __launch_bounds__(256) void quant_x_kernel(
    const float* __restrict__ x, unsigned char* __restrict__ xq,
    float* __restrict__ xs) {
  const int row = blockIdx.x;
  const int t = threadIdx.x;
  const float4* xr4 = (const float4*)(x + (size_t)row * K_DIM);

  float4 v[4];
  float am = 0.f;
#pragma unroll
  for (int i = 0; i < 4; ++i) {
    v[i] = xr4[t + 256 * i];
    am = fmaxf(am, fmaxf(fmaxf(fabsf(v[i].x), fabsf(v[i].y)),
                         fmaxf(fabsf(v[i].z), fabsf(v[i].w))));
  }
#pragma unroll
  for (int off = 32; off > 0; off >>= 1)
    am = fmaxf(am, __shfl_xor(am, off, 64));
  __shared__ float red[4];
  if ((t & 63) == 0) red[t >> 6] = am;
  __syncthreads();
  am = fmaxf(fmaxf(red[0], red[1]), fmaxf(red[2], red[3]));

  const float scale = fmaxf(am / 448.0f, 1e-12f);
  if (t == 0) xs[row] = scale;

  uint32_t* out = (uint32_t*)(xq + (size_t)row * K_DIM);
#pragma unroll
  for (int i = 0; i < 4; ++i) {
    float a0 = v[i].x / scale, a1 = v[i].y / scale;
    float a2 = v[i].z / scale, a3 = v[i].w / scale;
    uint32_t p = __builtin_amdgcn_cvt_pk_fp8_f32(a0, a1, 0, false);
    p = __builtin_amdgcn_cvt_pk_fp8_f32(a2, a3, p, true);
    out[t + 256 * i] = p;
  }
}

// ---------------------------------------------------------------------------
// Kernel 2: repack weight fp32 codes -> fp8 bytes (exact: values already on
// the e4m3 grid). 4 elements/thread.
// ---------------------------------------------------------------------------
__global__ __launch_bounds__(256) void quant_w_kernel(
    const float4* __restrict__ w, uint32_t* __restrict__ wq) {
  const int i = blockIdx.x * 256 + threadIdx.x;
  float4 v = w[i];
  uint32_t p = __builtin_amdgcn_cvt_pk_fp8_f32(v.x, v.y, 0, false);
  p = __builtin_amdgcn_cvt_pk_fp8_f32(v.z, v.w, p, true);
  wq[i] = p;
}

// ---------------------------------------------------------------------------
// Kernel 3: fp8 GEMM, m97 structure + XOR-swizzled LDS (kills the 8-way
// bank conflict of the 64B-stride row-major tile).
// LDS layout: row r's 16B chunk c is stored at slot (c ^ ((r>>1)&3)).
// Swizzle is applied on the staging side by choosing each lane's GLOBAL
// source chunk (LDS dst must stay base+lane*16 for global_load_lds).
// ---------------------------------------------------------------------------
__device__ __forceinline__ void async_copy16(const void* g, void* l) {
  __builtin_amdgcn_global_load_lds(
      (const __attribute__((address_space(1))) void*)g,
      (__attribute__((address_space(3))) void*)l, 16, 0, 0);
}

__global__ __launch_bounds__(256) void gemm_fp8_kernel(
    const unsigned char* __restrict__ Aq,  // [M,K] fp8
    const unsigned char* __restrict__ Bq,  // [N,K] fp8
    const float* __restrict__ xs,          // [M]
    const float* __restrict__ wscale,      // [N]
    const float* __restrict__ bias,        // [N]
    float* __restrict__ y) {               // [M,N]
  constexpr int BM = 128, BN = 128, BK = 64;
  __shared__ __align__(16) unsigned char smem[(BM + BN) * BK];  // 16 KiB
  unsigned char* sA = smem;
  unsigned char* sB = smem + BM * BK;

  const int t = threadIdx.x;
  const int bm = blockIdx.y * BM;
  const int bn = blockIdx.x * BN;

  // staging: thread t fills LDS slots t*16 and (t+256)*16 for each tile.
  // LDS slot (row=t>>2, s=t&3) holds global chunk c = s ^ g(row),
  // g(row) = (row>>1)&3.  g(row+64) == g(row), so one scol serves both.
  const int srow = t >> 2;
  const int scol = (((t & 3) ^ ((srow >> 1) & 3)) * 16);
  const unsigned char* Ag0 = Aq + (size_t)(bm + srow) * K_DIM + scol;
  const unsigned char* Ag1 = Aq + (size_t)(bm + srow + 64) * K_DIM + scol;
  const unsigned char* Bg0 = Bq + (size_t)(bn + srow) * K_DIM + scol;
  const unsigned char* Bg1 = Bq + (size_t)(bn + srow + 64) * K_DIM + scol;

  const int lane = t & 63;
  const int w = t >> 6;
  const int wm = (w >> 1) * 64;
  const int wn = (w & 1) * 64;
  const int lrow = lane & 15;   // A-row / B-col / C-col
  const int lq = lane >> 4;     // quad: k-base (lq*8), C-row base (lq*4)
  // lane-constant XOR mask for swizzled fragment reads:
  // addr = row*64 + ((kk + lq*8) ^ xm)   [XOR distributes over <<4]
  const int xm = ((lrow >> 1) & 3) << 4;

  v4f acc[4][4];
#pragma unroll
  for (int i = 0; i < 4; ++i)
#pragma unroll
    for (int j = 0; j < 4; ++j) acc[i][j] = {0.f, 0.f, 0.f, 0.f};

  for (int k0 = 0; k0 < K_DIM; k0 += BK) {
    __syncthreads();
    async_copy16(Ag0 + k0, sA + t * 16);
    async_copy16(Ag1 + k0, sA + (t + 256) * 16);
    async_copy16(Bg0 + k0, sB + t * 16);
    async_copy16(Bg1 + k0, sB + (t + 256) * 16);
    __syncthreads();  // compiler emits s_waitcnt vmcnt(0) before s_barrier

#pragma unroll
    for (int kk = 0; kk < BK; kk += 32) {
      const int koff = (kk + lq * 8) ^ xm;
      long long a_frag[4], b_frag[4];
#pragma unroll
      for (int i = 0; i < 4; ++i)
        a_frag[i] = *(const long long*)(sA + (wm + i * 16 + lrow) * BK + koff);
#pragma unroll
      for (int j = 0; j < 4; ++j)
        b_frag[j] = *(const long long*)(sB + (wn + j * 16 + lrow) * BK + koff);
#pragma unroll
      for (int i = 0; i < 4; ++i)
#pragma unroll
        for (int j = 0; j < 4; ++j)
          acc[i][j] = __builtin_amdgcn_mfma_f32_16x16x32_fp8_fp8(
              a_frag[i], b_frag[j], acc[i][j], 0, 0, 0);
    }
  }

  // epilogue: C/D layout col=lane&15, row=(lane>>4)*4+reg
  float xsv[4][4];
#pragma unroll
  for (int i = 0; i < 4; ++i)
#pragma unroll
    for (int r = 0; r < 4; ++r)
      xsv[i][r] = xs[bm + wm + i * 16 + lq * 4 + r];

#pragma unroll
  for (int j = 0; j < 4; ++j) {
    const int col = bn + wn + j * 16 + lrow;
    const float wsc = wscale[col];
    const float bv = bias[col];
#pragma unroll
    for (int i = 0; i < 4; ++i) {
      const int row0 = bm + wm + i * 16 + lq * 4;
#pragma unroll
      for (int r = 0; r < 4; ++r)
        y[(size_t)(row0 + r) * N_DIM + col] =
            acc[i][j][r] * xsv[i][r] * wsc + bv;
    }
  }
}

// ---------------------------------------------------------------------------
extern "C" void kernel_launch(void* const* d_in, const int* in_sizes, int n_in,
                              void* d_out, int out_size, void* d_ws,
                              size_t ws_size, hipStream_t stream) {
  const float* x = (const float*)d_in[0];       // [M,K]
  const float* w = (const float*)d_in[1];       // [N,K] fp8 codes in fp32
  const float* wscale = (const float*)d_in[2];  // [N,1]
  const float* bias = (const float*)d_in[3];    // [N]
  float* y = (float*)d_out;                     // [M,N]

  unsigned char* xq = (unsigned char*)d_ws;                  // 16 MiB
  unsigned char* wq = xq + (size_t)M_DIM * K_DIM;            // 64 MiB
  float* xs = (float*)(wq + (size_t)N_DIM * K_DIM);          // 16 KiB

  quant_x_kernel<<<M_DIM, 256, 0, stream>>>(x, xq, xs);
  quant_w_kernel<<<((size_t)N_DIM * K_DIM / 4) / 256, 256, 0, stream>>>(
      (const float4*)w, (uint32_t*)wq);
  dim3 grid(N_DIM / 128, M_DIM / 128);
  gemm_fp8_kernel<<<grid, 256, 0, stream>>>(xq, wq, xs, wscale, bias, y);
}